// Round 11
// baseline (175.381 us; speedup 1.0000x reference)
//
#include <hip/hip_runtime.h>

// Reference-exact fp32 d2: no FMA contraction. d2 = (sqn+sqm) + dot' with
// dot' built from (-2x) pre-scaled m-points is bit-identical to the ref's
// (sqn+sqm) - 2*dot (power-of-2 scaling / negation commute with rounding).
// Self-distance: dt(n,n) = -2*sq_n exactly, so d2(n,n) == +0.0 exactly.
// v_pk_mul_f32 / v_pk_add_f32 are per-lane IEEE-identical to scalar ops.
//
// Comparison domains (exact, dataset-independent):
//  argmax: signed-int compare on d2 bits (positive floats order-isomorphic
//    to bits; rounding-negative d2 -> deep negative, never beats positive,
//    matching ref clamp-to-0 which also loses to any positive distance).
//  argmin: unsigned compare on (bits - 1): +0.0 -> 0xFFFFFFFF (never wins =
//    ref's dist==0 -> 1e6 mask); negative d2 -> >= 0x7FFFFFFF (never wins =
//    ref clamp->0->masked); positive ordering and exact ties preserved.
#pragma clang fp contract(off)

typedef float v2f __attribute__((ext_vector_type(2)));

#define NBATCH 256   // B*L
#define NPTS   512   // points per batch
#define JDIM   128   // logit dim
#define NPAIR  (NBATCH * NPTS)   // 131072
#define PADC   18    // tile column pitch (floats): 8B-aligned, 16 start banks

// ---------------- K1: per-point argmax / masked-argmin of d2 ----------------
// (R10 form, unchanged — best-known-equal.)
__global__ __launch_bounds__(512) void argmm_kernel(
    const float* __restrict__ xyz,   // [NBATCH, NPTS, 3]
    int* __restrict__ pmax,          // [NBATCH*NPTS]
    int* __restrict__ pmin)          // [NBATCH*NPTS]
{
    __shared__ int smem[8192];               // 32 KB, phase-aliased
    float4* xyzD = (float4*)smem;

    const int t  = threadIdx.x;
    const int bl = blockIdx.x >> 2;
    const int qq = blockIdx.x & 3;           // point-quarter of this block
    const float* xp = xyz + (size_t)bl * NPTS * 3;

    // stage all 512 points, scaled & duplicated; sq in ref order from raw
    {
        float x = xp[3 * t], y = xp[3 * t + 1], z = xp[3 * t + 2];
        float sq = (x * x + y * y) + z * z;  // matches np.sum(x*x,-1)
        float x2 = -2.0f * x, y2 = -2.0f * y, z2 = -2.0f * z;
        xyzD[2 * t]     = make_float4(x2, x2, y2, y2);
        xyzD[2 * t + 1] = make_float4(z2, z2, sq, sq);
    }

    // own 4 points RAW from global, packed as 2 v2f pairs
    const int g = t & 31, s = t >> 5;
    const int pbase = qq * 128 + g * 4;
    v2f ox2[2], oy2[2], oz2[2], oq2[2];
    {
        const float4* own = (const float4*)(xp + 3 * pbase);
        float4 o0 = own[0], o1 = own[1], o2 = own[2];
        ox2[0] = (v2f){o0.x, o0.w};  oy2[0] = (v2f){o0.y, o1.x};  oz2[0] = (v2f){o0.z, o1.y};
        ox2[1] = (v2f){o1.z, o2.y};  oy2[1] = (v2f){o1.w, o2.z};  oz2[1] = (v2f){o2.x, o2.w};
        #pragma unroll
        for (int j = 0; j < 2; ++j)
            oq2[j] = (ox2[j] * ox2[j] + oy2[j] * oy2[j]) + oz2[j] * oz2[j];
    }
    __syncthreads();

    const int mbase = s * 32;
    int bmax[4], ima[4], imi[4]; unsigned bmin[4];
    #pragma unroll
    for (int k = 0; k < 4; ++k) {
        bmax[k] = (int)0x80000000;
        bmin[k] = 0xFFFFFFFFu;
        ima[k] = mbase; imi[k] = mbase;
    }

    const v2f* xd = (const v2f*)xyzD;
    #pragma unroll 8
    for (int mm = 0; mm < 32; ++mm) {
        int m = mbase + mm;
        v2f qxx = xd[4 * m + 0];
        v2f qyy = xd[4 * m + 1];
        v2f qzz = xd[4 * m + 2];
        v2f qss = xd[4 * m + 3];
        #pragma unroll
        for (int j = 0; j < 2; ++j) {
            v2f dt = (ox2[j] * qxx + oy2[j] * qyy) + oz2[j] * qzz;  // == -2*dot
            v2f d2 = (oq2[j] + qss) + dt;    // bits == ref d2 (pre-clamp)
            int b0 = __float_as_int(d2.x);
            int b1 = __float_as_int(d2.y);
            const int k0 = 2 * j, k1 = 2 * j + 1;

            bool g0 = b0 > bmax[k0];
            ima[k0] = g0 ? m : ima[k0];  bmax[k0] = g0 ? b0 : bmax[k0];
            unsigned u0 = (unsigned)b0 - 1u;
            bool l0 = u0 < bmin[k0];
            imi[k0] = l0 ? m : imi[k0];  bmin[k0] = l0 ? u0 : bmin[k0];

            bool g1 = b1 > bmax[k1];
            ima[k1] = g1 ? m : ima[k1];  bmax[k1] = g1 ? b1 : bmax[k1];
            unsigned u1 = (unsigned)b1 - 1u;
            bool l1 = u1 < bmin[k1];
            imi[k1] = l1 ? m : imi[k1];  bmin[k1] = l1 ? u1 : bmin[k1];
        }
    }
    __syncthreads();   // all xyzD reads done; safe to alias merge scratch

    int*      mv = smem;                     // [16][128]
    int*      mi = smem + 2048;
    unsigned* nv = (unsigned*)smem + 4096;
    int*      ni = smem + 6144;
    #pragma unroll
    for (int k = 0; k < 4; ++k) {
        int pt = g * 4 + k;
        mv[s * 128 + pt] = bmax[k];  mi[s * 128 + pt] = ima[k];
        nv[s * 128 + pt] = bmin[k];  ni[s * 128 + pt] = imi[k];
    }
    __syncthreads();

    if (t < 256) {
        const int pt = t & 127;
        const int out_idx = bl * NPTS + qq * 128 + pt;
        if (t < 128) {
            int bv = mv[pt]; int bi = mi[pt];
            #pragma unroll
            for (int ss = 1; ss < 16; ++ss) {
                int v = mv[ss * 128 + pt]; int i = mi[ss * 128 + pt];
                bool w = v > bv; bi = w ? i : bi; bv = w ? v : bv;
            }
            pmax[out_idx] = bi;
        } else {
            unsigned sv = nv[pt]; int si = ni[pt];
            #pragma unroll
            for (int ss = 1; ss < 16; ++ss) {
                unsigned u = nv[ss * 128 + pt]; int j = ni[ss * 128 + pt];
                bool x = u < sv; si = x ? j : si; sv = x ? u : sv;
            }
            pmin[out_idx] = si;
        }
    }
}

// ---------------- K2: transposed-tile sim gathers + last-block mean ---------
// Grid 2048 = 256 batches x 8 chunks of 16 ypred rows. Thread t owns COLUMN
// (point) t: 16 coalesced b32 global loads = its own a-column in registers;
// tile stored column-major (pitch 18) so each partner gather is 8 aligned
// b64 LDS reads. Final mean by the last block (threadfence + counter).
__global__ __launch_bounds__(512) void sim_kernel(
    const float* __restrict__ ypred,   // [NBATCH, JDIM, NPTS]
    const int* __restrict__ pmax,
    const int* __restrict__ pmin,
    float* __restrict__ partials,      // [2048]
    unsigned* __restrict__ counter,    // pre-zeroed
    float* __restrict__ out)
{
    __shared__ float L[NPTS * PADC];   // 36 KB, column-major
    __shared__ float wred[8];
    __shared__ bool  amLast;

    const int t  = threadIdx.x;
    const int bl = blockIdx.x >> 3;
    const int c  = blockIdx.x & 7;     // j-chunk

    // partner indices: issue early, land under the staging loads
    const int pma = pmax[bl * NPTS + t];
    const int pmi = pmin[bl * NPTS + t];

    // own a-column straight from global: 16 coalesced b32 (full 256B lines)
    const float* base = ypred + (size_t)bl * JDIM * NPTS + (size_t)c * 16 * NPTS;
    float a[16];
    #pragma unroll
    for (int r = 0; r < 16; ++r)
        a[r] = base[r * NPTS + t];

    // stage transposed: 8 aligned b64 writes (72t bytes, 8B-aligned)
    float2* col = (float2*)(L + PADC * t);
    #pragma unroll
    for (int r = 0; r < 8; ++r)
        col[r] = make_float2(a[2 * r], a[2 * r + 1]);
    __syncthreads();

    // gathers: contiguous columns -> 8 b64 each, near-baseline banking
    const float2* bcol = (const float2*)(L + PADC * pma);
    const float2* ccol = (const float2*)(L + PADC * pmi);
    float accP = 0.0f, accM = 0.0f;
    #pragma unroll
    for (int r = 0; r < 8; ++r) {
        float2 bb = bcol[r];
        float2 cc = ccol[r];
        accP = fmaf(a[2 * r],     bb.x, accP);   // same per-chunk fmaf order
        accP = fmaf(a[2 * r + 1], bb.y, accP);   // as prior rounds
        accM = fmaf(a[2 * r],     cc.x, accM);
        accM = fmaf(a[2 * r + 1], cc.y, accM);
    }

    float d = accP - accM;
    #pragma unroll
    for (int off = 32; off > 0; off >>= 1)
        d += __shfl_down(d, off);
    if ((t & 63) == 0) wred[t >> 6] = d;
    __syncthreads();
    if (t == 0) {
        float ssum = 0.0f;
        #pragma unroll
        for (int w = 0; w < 8; ++w) ssum += wred[w];
        partials[blockIdx.x] = ssum;
        __threadfence();                        // release partials
        unsigned old = atomicAdd(counter, 1u);  // device-scope
        amLast = (old == 2047u);
    }
    __syncthreads();

    if (amLast) {                               // last block reduces all
        __threadfence();                        // acquire others' partials
        float v = (partials[t] + partials[t + 512])
                + (partials[t + 1024] + partials[t + 1536]);
        #pragma unroll
        for (int off = 32; off > 0; off >>= 1)
            v += __shfl_down(v, off);
        if ((t & 63) == 0) wred[t >> 6] = v;
        __syncthreads();
        if (t == 0) {
            float s = 0.0f;
            #pragma unroll
            for (int w = 0; w < 8; ++w) s += wred[w];
            out[0] = s * (1.0f / (float)NPAIR);
        }
    }
}

extern "C" void kernel_launch(void* const* d_in, const int* in_sizes, int n_in,
                              void* d_out, int out_size, void* d_ws, size_t ws_size,
                              hipStream_t stream) {
    const float* ypred = (const float*)d_in[0];   // [8,32,128,512] f32
    const float* xyz   = (const float*)d_in[1];   // [8,32,512,3]  f32

    // ws: pmax[131072], pmin[131072] ints, partials[2048] floats, counter
    int*      pmax     = (int*)d_ws;
    int*      pmin     = pmax + NPAIR;
    float*    partials = (float*)(pmin + NPAIR);
    unsigned* counter  = (unsigned*)(partials + 2048);
    float*    out      = (float*)d_out;

    hipMemsetAsync(counter, 0, sizeof(unsigned), stream);  // capture-legal
    argmm_kernel<<<4 * NBATCH, 512, 0, stream>>>(xyz, pmax, pmin);
    sim_kernel<<<8 * NBATCH, 512, 0, stream>>>(ypred, pmax, pmin,
                                               partials, counter, out);
}

// Round 12
// 116.448 us; speedup vs baseline: 1.5061x; 1.5061x over previous
//
#include <hip/hip_runtime.h>

// Reference-exact fp32 d2: no FMA contraction. d2 = (sqn+sqm) + dot' with
// dot' built from (-2x) pre-scaled m-points is bit-identical to the ref's
// (sqn+sqm) - 2*dot (power-of-2 scaling / negation commute with rounding).
// Self-distance: dt(n,n) = -2*sq_n exactly, so d2(n,n) == +0.0 exactly.
// v_pk_mul_f32 / v_pk_add_f32 are per-lane IEEE-identical to scalar ops.
//
// Comparison domains (exact, dataset-independent):
//  argmax: signed-int compare on d2 bits (positive floats order-isomorphic
//    to bits; rounding-negative d2 -> deep negative, never beats positive,
//    matching ref clamp-to-0 which also loses to any positive distance).
//  argmin: unsigned compare on (bits - 1): +0.0 -> 0xFFFFFFFF (never wins =
//    ref's dist==0 -> 1e6 mask); negative d2 -> >= 0x7FFFFFFF (never wins =
//    ref clamp->0->masked); positive ordering and exact ties preserved.
//
// HW rule learned R8/R11: NO device-scope atomics or __threadfence in the
// hot path on MI355X — same-address atomics serialize cross-XCD and fences
// force per-XCD L2 writeback; both showed up as massive all-idle stalls.
#pragma clang fp contract(off)

typedef float v2f __attribute__((ext_vector_type(2)));

#define NBATCH 256   // B*L
#define NPTS   512   // points per batch
#define JDIM   128   // logit dim
#define NPAIR  (NBATCH * NPTS)   // 131072
#define PITCH  17    // K2 tile column pitch (floats); odd -> all 32 banks

// ---------------- K1: per-point argmax / masked-argmin of d2 ----------------
// (R10 form, unchanged.) Grid 1024 = 4 blocks/batch. 512 thr, 32 KB LDS.
__global__ __launch_bounds__(512) void argmm_kernel(
    const float* __restrict__ xyz,   // [NBATCH, NPTS, 3]
    int* __restrict__ pmax,          // [NBATCH*NPTS]
    int* __restrict__ pmin)          // [NBATCH*NPTS]
{
    __shared__ int smem[8192];               // 32 KB, phase-aliased
    float4* xyzD = (float4*)smem;

    const int t  = threadIdx.x;
    const int bl = blockIdx.x >> 2;
    const int qq = blockIdx.x & 3;           // point-quarter of this block
    const float* xp = xyz + (size_t)bl * NPTS * 3;

    // stage all 512 points, scaled & duplicated; sq in ref order from raw
    {
        float x = xp[3 * t], y = xp[3 * t + 1], z = xp[3 * t + 2];
        float sq = (x * x + y * y) + z * z;  // matches np.sum(x*x,-1)
        float x2 = -2.0f * x, y2 = -2.0f * y, z2 = -2.0f * z;
        xyzD[2 * t]     = make_float4(x2, x2, y2, y2);
        xyzD[2 * t + 1] = make_float4(z2, z2, sq, sq);
    }

    // own 4 points RAW from global, packed as 2 v2f pairs
    const int g = t & 31, s = t >> 5;
    const int pbase = qq * 128 + g * 4;
    v2f ox2[2], oy2[2], oz2[2], oq2[2];
    {
        const float4* own = (const float4*)(xp + 3 * pbase);
        float4 o0 = own[0], o1 = own[1], o2 = own[2];
        ox2[0] = (v2f){o0.x, o0.w};  oy2[0] = (v2f){o0.y, o1.x};  oz2[0] = (v2f){o0.z, o1.y};
        ox2[1] = (v2f){o1.z, o2.y};  oy2[1] = (v2f){o1.w, o2.z};  oz2[1] = (v2f){o2.x, o2.w};
        #pragma unroll
        for (int j = 0; j < 2; ++j)
            oq2[j] = (ox2[j] * ox2[j] + oy2[j] * oy2[j]) + oz2[j] * oz2[j];
    }
    __syncthreads();

    const int mbase = s * 32;
    int bmax[4], ima[4], imi[4]; unsigned bmin[4];
    #pragma unroll
    for (int k = 0; k < 4; ++k) {
        bmax[k] = (int)0x80000000;
        bmin[k] = 0xFFFFFFFFu;
        ima[k] = mbase; imi[k] = mbase;
    }

    const v2f* xd = (const v2f*)xyzD;
    #pragma unroll 8
    for (int mm = 0; mm < 32; ++mm) {
        int m = mbase + mm;
        v2f qxx = xd[4 * m + 0];
        v2f qyy = xd[4 * m + 1];
        v2f qzz = xd[4 * m + 2];
        v2f qss = xd[4 * m + 3];
        #pragma unroll
        for (int j = 0; j < 2; ++j) {
            v2f dt = (ox2[j] * qxx + oy2[j] * qyy) + oz2[j] * qzz;  // == -2*dot
            v2f d2 = (oq2[j] + qss) + dt;    // bits == ref d2 (pre-clamp)
            int b0 = __float_as_int(d2.x);
            int b1 = __float_as_int(d2.y);
            const int k0 = 2 * j, k1 = 2 * j + 1;

            bool g0 = b0 > bmax[k0];
            ima[k0] = g0 ? m : ima[k0];  bmax[k0] = g0 ? b0 : bmax[k0];
            unsigned u0 = (unsigned)b0 - 1u;
            bool l0 = u0 < bmin[k0];
            imi[k0] = l0 ? m : imi[k0];  bmin[k0] = l0 ? u0 : bmin[k0];

            bool g1 = b1 > bmax[k1];
            ima[k1] = g1 ? m : ima[k1];  bmax[k1] = g1 ? b1 : bmax[k1];
            unsigned u1 = (unsigned)b1 - 1u;
            bool l1 = u1 < bmin[k1];
            imi[k1] = l1 ? m : imi[k1];  bmin[k1] = l1 ? u1 : bmin[k1];
        }
    }
    __syncthreads();   // all xyzD reads done; safe to alias merge scratch

    int*      mv = smem;                     // [16][128]
    int*      mi = smem + 2048;
    unsigned* nv = (unsigned*)smem + 4096;
    int*      ni = smem + 6144;
    #pragma unroll
    for (int k = 0; k < 4; ++k) {
        int pt = g * 4 + k;
        mv[s * 128 + pt] = bmax[k];  mi[s * 128 + pt] = ima[k];
        nv[s * 128 + pt] = bmin[k];  ni[s * 128 + pt] = imi[k];
    }
    __syncthreads();

    if (t < 256) {
        const int pt = t & 127;
        const int out_idx = bl * NPTS + qq * 128 + pt;
        if (t < 128) {
            int bv = mv[pt]; int bi = mi[pt];
            #pragma unroll
            for (int ss = 1; ss < 16; ++ss) {
                int v = mv[ss * 128 + pt]; int i = mi[ss * 128 + pt];
                bool w = v > bv; bi = w ? i : bi; bv = w ? v : bv;
            }
            pmax[out_idx] = bi;
        } else {
            unsigned sv = nv[pt]; int si = ni[pt];
            #pragma unroll
            for (int ss = 1; ss < 16; ++ss) {
                unsigned u = nv[ss * 128 + pt]; int j = ni[ss * 128 + pt];
                bool x = u < sv; si = x ? j : si; sv = x ? u : sv;
            }
            pmin[out_idx] = si;
        }
    }
}

// ---------------- K2: column-major pitch-17 tile sim gathers ----------------
// Grid 2048 = 256 batches x 8 chunks of 16 ypred rows. Thread t owns COLUMN
// (point) t: 16 coalesced b32 global loads = own a-column in registers.
// Tile column-major, pitch 17 (odd): 17t mod 32 covers all banks -> staging
// writes (ds_write2_b32 x8) and partner gathers (ds_read2_b32 x8 each) are
// ~conflict-free. No fences, no atomics.
__global__ __launch_bounds__(512) void sim_kernel(
    const float* __restrict__ ypred,   // [NBATCH, JDIM, NPTS]
    const int* __restrict__ pmax,
    const int* __restrict__ pmin,
    float* __restrict__ partials)      // [2048]
{
    __shared__ float L[NPTS * PITCH];  // 34 KB, column-major
    __shared__ float wred[8];

    const int t  = threadIdx.x;
    const int bl = blockIdx.x >> 3;
    const int c  = blockIdx.x & 7;     // j-chunk

    // partner indices: issue early, land under the staging loads
    const int pma = pmax[bl * NPTS + t];
    const int pmi = pmin[bl * NPTS + t];

    // own a-column from global: 16 coalesced b32 (each = one full 256B line/wave)
    const float* base = ypred + (size_t)bl * JDIM * NPTS + (size_t)c * 16 * NPTS;
    float a[16];
    #pragma unroll
    for (int r = 0; r < 16; ++r)
        a[r] = base[r * NPTS + t];

    // stage own column: 16 consecutive b32 -> 8 ds_write2_b32, all-bank spread
    float* col = L + PITCH * t;
    #pragma unroll
    for (int r = 0; r < 16; ++r)
        col[r] = a[r];
    __syncthreads();

    // partner gathers: contiguous -> 8 ds_read2_b32 each, 2-way avg (free)
    const float* bcol = L + PITCH * pma;
    const float* ccol = L + PITCH * pmi;
    float accP = 0.0f, accM = 0.0f;
    #pragma unroll
    for (int r = 0; r < 16; ++r) {
        accP = fmaf(a[r], bcol[r], accP);   // same per-chunk fmaf order as R7
        accM = fmaf(a[r], ccol[r], accM);
    }

    float d = accP - accM;
    #pragma unroll
    for (int off = 32; off > 0; off >>= 1)
        d += __shfl_down(d, off);
    if ((t & 63) == 0) wred[t >> 6] = d;
    __syncthreads();
    if (t == 0) {
        float ssum = 0.0f;
        #pragma unroll
        for (int w = 0; w < 8; ++w) ssum += wred[w];
        partials[blockIdx.x] = ssum;
    }
}

// ---------------- K3: final mean over 2048 partials -------------------------
__global__ __launch_bounds__(1024) void reduce_mean_kernel(
    const float* __restrict__ partials, float* __restrict__ out)
{
    const int t = threadIdx.x;
    float v = partials[t] + partials[t + 1024];
    #pragma unroll
    for (int off = 32; off > 0; off >>= 1)
        v += __shfl_down(v, off);

    __shared__ float w[16];
    if ((t & 63) == 0) w[t >> 6] = v;
    __syncthreads();
    if (t == 0) {
        float s = 0.0f;
        #pragma unroll
        for (int i = 0; i < 16; ++i) s += w[i];
        out[0] = s * (1.0f / (float)NPAIR);
    }
}

extern "C" void kernel_launch(void* const* d_in, const int* in_sizes, int n_in,
                              void* d_out, int out_size, void* d_ws, size_t ws_size,
                              hipStream_t stream) {
    const float* ypred = (const float*)d_in[0];   // [8,32,128,512] f32
    const float* xyz   = (const float*)d_in[1];   // [8,32,512,3]  f32

    // ws: pmax[131072], pmin[131072] ints, partials[2048] floats (~1.06 MB)
    int*   pmax     = (int*)d_ws;
    int*   pmin     = pmax + NPAIR;
    float* partials = (float*)(pmin + NPAIR);
    float* out      = (float*)d_out;

    argmm_kernel<<<4 * NBATCH, 512, 0, stream>>>(xyz, pmax, pmin);
    sim_kernel<<<8 * NBATCH, 512, 0, stream>>>(ypred, pmax, pmin, partials);
    reduce_mean_kernel<<<1, 1024, 0, stream>>>(partials, out);
}